// Round 14
// baseline (471.574 us; speedup 1.0000x reference)
//
#include <hip/hip_runtime.h>
#include <stdint.h>

// Periodic radius-graph neighbor list (AlphaNet). B=16, N=256, C=27, M=6912.
// Outputs (flat f32 concat): dist [B,N,M], dvec [B,N,M,3], num_neighbors_image [B].
// keep = (1e-4 < dsqr <= 25) AND stable-sort rank < 32
//      == key (f32bits(dsqr)<<32 | m) among the 32 smallest within-radius keys.
//
// R14: R13 (zero global atomics, edges+sweep) with edges' metadata path slimmed:
//  - sws (28.3 MB slot bytes) zeroed by hipMemsetAsync (fill path ~5 us)
//  - rank-scan winners store their slot byte DIRECTLY to global (<=32/receiver)
//  - edges loses the LDS slot array, its zeroing, the 28.3 MB export, a barrier
// Measured so far: sweep 82 us (~6.0 TB/s = 95% of fill rate), edges 23 us
// (vs ~13 us compute floor). Same-line global atomics were the R10-R12 trap.

constexpr int B_ = 16, N_ = 256, C_ = 27;
constexpr int M_ = N_ * C_;            // 6912
constexpr int MAXC = 256;              // LDS candidate slots; mean ~78
constexpr int KMAX = 32;
constexpr int NR   = B_ * N_;          // 4096 receivers
constexpr int DGPR = M_ / 4;           // 1728 slot words per receiver
constexpr int VG   = 3 * M_ / 4;       // 5184 dvec groups per receiver
constexpr int DG = NR * DGPR;
constexpr int NG = DG + NR * VG;       // 28,311,552 float4 groups = dist||dvec
constexpr int SWEEP_BLOCKS = 2048;

typedef float vfloat4 __attribute__((ext_vector_type(4)));

__device__ __forceinline__ void nt_store4(float* p, float a, float b, float c, float d) {
    vfloat4 v; v.x = a; v.y = b; v.z = c; v.w = d;
    __builtin_nontemporal_store(v, (vfloat4*)p);
}

__global__ __launch_bounds__(256)
void edges_kernel(const float* __restrict__ pos,    // [B,N,3]
                  const float* __restrict__ cell,   // [B,3,3]
                  int*   __restrict__ ecnt,         // [NR] kept count (plain store)
                  unsigned char* __restrict__ sbytes, // [NR * M_] slot bytes (pre-zeroed)
                  float4*  __restrict__ kws)        // [NR * KMAX] dx,dy,dz,dist
{
#pragma clang fp contract(off)
    __shared__ float offx[C_], offy[C_], offz[C_];
    __shared__ unsigned long long keys[MAXC];
    __shared__ int cnt;

    const int bi  = blockIdx.x;
    const int b   = bi >> 8;
    const int i   = bi & 255;
    const int tid = threadIdx.x;

    const float* pb = pos + b * N_ * 3;
    const float pjx = pb[tid * 3 + 0], pjy = pb[tid * 3 + 1], pjz = pb[tid * 3 + 2];
    const float pix = pb[i * 3 + 0],   piy = pb[i * 3 + 1],   piz = pb[i * 3 + 2];

    if (tid < C_) {
        const float n1 = (float)(tid / 9 - 1);
        const float n2 = (float)((tid / 3) % 3 - 1);
        const float n3 = (float)(tid % 3 - 1);
        const float* cb = cell + b * 9;
        offx[tid] = n1 * cb[0] + n2 * cb[3] + n3 * cb[6];
        offy[tid] = n1 * cb[1] + n2 * cb[4] + n3 * cb[7];
        offz[tid] = n1 * cb[2] + n2 * cb[5] + n3 * cb[8];
    }
    if (tid == 0) cnt = 0;
    __syncthreads();

    // pass 1: bit-exact numpy order: s = pj + off; d = pi - s; ((dx*dx+dy*dy)+dz*dz)
    #pragma unroll 1
    for (int c = 0; c < C_; ++c) {
        const float sx = pjx + offx[c], sy = pjy + offy[c], sz = pjz + offz[c];
        const float dx = pix - sx, dy = piy - sy, dz = piz - sz;
        const float dsq = dx * dx + dy * dy + dz * dz;
        if (dsq <= 25.0f && dsq > 1e-4f) {
            const int idx = atomicAdd(&cnt, 1);              // LDS atomic only
            if (idx < MAXC)
                keys[idx] = ((unsigned long long)__float_as_uint(dsq) << 32)
                          | (unsigned)(tid * C_ + c);
        }
    }
    __syncthreads();

    int K = cnt; if (K > MAXC) K = MAXC;
    if (tid == 0)
        ecnt[bi] = (K < KMAX) ? K : KMAX;                    // plain store

    // rank scan (keys unique) -> winners write slot byte straight to global
    // (sbytes pre-zeroed by memset) + kept table (bit-exact recompute)
    for (int idx = tid; idx < K; idx += 256) {
        const unsigned long long key = keys[idx];
        int r = 0;
        for (int q = 0; q < K; ++q) r += (keys[q] < key) ? 1 : 0;
        if (r < KMAX) {
            const int m = (int)(key & 0xffffffffu);
            sbytes[(size_t)bi * M_ + m] = (unsigned char)(r + 1);
            const int j = m / C_;
            const int c = m - j * C_;
            const float sx = pb[j * 3 + 0] + offx[c];
            const float sy = pb[j * 3 + 1] + offy[c];
            const float sz = pb[j * 3 + 2] + offz[c];
            const float dx = pix - sx, dy = piy - sy, dz = piz - sz;
            const float dsq = dx * dx + dy * dy + dz * dz;
            kws[bi * KMAX + r] = make_float4(dx, dy, dz, sqrtf(dsq));
        }
    }
}

__global__ __launch_bounds__(256)
void sweep_kernel(const uint32_t* __restrict__ sws,  // [NR * DGPR] (== sbytes)
                  const float4*  __restrict__ kws,   // [NR * KMAX]
                  const int*     __restrict__ ecnt,  // [NR]
                  float* __restrict__ out,           // dist||dvec, NG float4 groups
                  float* __restrict__ nn)            // [B]
{
    // nn reduction: block 0, lanes 0..15 each sum 256 contiguous ints
    if (blockIdx.x == 0 && threadIdx.x < B_) {
        const int* e = ecnt + threadIdx.x * N_;
        int s = 0;
        for (int k = 0; k < N_; ++k) s += e[k];
        nn[threadIdx.x] = (float)s;
    }

    const int stride = SWEEP_BLOCKS * 256;
    for (int g = blockIdx.x * 256 + threadIdx.x; g < NG; g += stride) {
        float o0 = 0.f, o1 = 0.f, o2 = 0.f, o3 = 0.f;
        if (g < DG) {
            const uint32_t s4 = sws[g];
            if (s4) {
                const int bi = g / DGPR;
                const float4* kb = kws + bi * KMAX;
                uint32_t s;
                s = s4 & 0xffu;         if (s) o0 = kb[s - 1].w;
                s = (s4 >> 8) & 0xffu;  if (s) o1 = kb[s - 1].w;
                s = (s4 >> 16) & 0xffu; if (s) o2 = kb[s - 1].w;
                s = (s4 >> 24) & 0xffu; if (s) o3 = kb[s - 1].w;
            }
        } else {
            const int h  = g - DG;
            const int bi = h / VG;
            const int hh = h - bi * VG;
            const int e0 = 4 * hh;
            const int m0 = e0 / 3;
            const int m1 = (e0 + 3) / 3;
            const unsigned char* sb = (const unsigned char*)sws + (size_t)bi * M_;
            const uint32_t sA = sb[m0], sB = sb[m1];
            if ((sA | sB) != 0) {
                const float4* kb = kws + bi * KMAX;
                float o[4] = {0.f, 0.f, 0.f, 0.f};
                #pragma unroll
                for (int u = 0; u < 4; ++u) {
                    const int e = e0 + u;
                    const int m = e / 3;
                    const int d = e - 3 * m;
                    const uint32_t s = (m == m0) ? sA : sB;
                    if (s) o[u] = (&kb[s - 1].x)[d];
                }
                o0 = o[0]; o1 = o[1]; o2 = o[2]; o3 = o[3];
            }
        }
        nt_store4(out + 4 * (size_t)g, o0, o1, o2, o3);
    }
}

extern "C" void kernel_launch(void* const* d_in, const int* in_sizes, int n_in,
                              void* d_out, int out_size, void* d_ws, size_t ws_size,
                              hipStream_t stream)
{
    const float* pos  = (const float*)d_in[0];
    const float* cell = (const float*)d_in[1];
    float* out = (float*)d_out;                       // dist || dvec || nn
    float* nn  = out + (size_t)NR * M_ * 4;

    uint32_t* sws = (uint32_t*)d_ws;                                  // 28.3 MB
    float4*   kws = (float4*)((char*)d_ws + (size_t)NR * DGPR * 4);   // 2 MB
    int*      ecnt = (int*)((char*)d_ws + (size_t)NR * DGPR * 4 + (size_t)NR * KMAX * 16);

    // zero slot bytes via the rocclr fill path (~5 us for 28.3 MB)
    (void)hipMemsetAsync(sws, 0, (size_t)NR * DGPR * 4, stream);
    edges_kernel<<<dim3(NR), dim3(256), 0, stream>>>(pos, cell, ecnt,
                                                     (unsigned char*)sws, kws);
    sweep_kernel<<<dim3(SWEEP_BLOCKS), dim3(256), 0, stream>>>(sws, kws, ecnt, out, nn);
}